// Round 4
// baseline (189.425 us; speedup 1.0000x reference)
//
#include <hip/hip_runtime.h>
#include <math.h>

#define NPTS 4096
#define BATCH 4
#define KNB 16
#define BIG 3.0e38f

// ---------------------------------------------------------------------------
// Bitonic sort of 64 (d,slot) pairs, one per lane, ascending in d.
// ---------------------------------------------------------------------------
__device__ __forceinline__ void bsort_stage(float& d, int& s, int lane, int k, int j) {
  const float od = __shfl_xor(d, j);
  const int   os = __shfl_xor(s, j);
  const bool keepMin = ((lane & k) == 0) == ((lane & j) == 0);
  const bool takeO = keepMin ? (od < d) : (od > d);
  d = takeO ? od : d;
  s = takeO ? os : s;
}

__device__ __forceinline__ void bitonic_sort64(float& d, int& s, int lane) {
#pragma unroll
  for (int k = 2; k <= 64; k <<= 1) {
#pragma unroll
    for (int j = k >> 1; j >= 1; j >>= 1)
      bsort_stage(d, s, lane, k, j);
  }
}

// ---------------------------------------------------------------------------
// Kernel 1: one WAVE per (query i, batch b, dataset ds). 4 waves/block, no
// LDS, no barriers. Exact 16-NN via running-threshold insertion scan:
//   - chunk 0 (64 cands) seeds the sorted top-16 via one bitonic sort
//   - chunks 1..63: ballot(d2 < tau); each survivor does a wave-wide
//     sorted-shift insert into the list held in lanes 0..15.
// ---------------------------------------------------------------------------
__global__ __launch_bounds__(256)
void knn_kappa_kernel(const float* __restrict__ ori,
                      const float* __restrict__ adv,
                      const float* __restrict__ nrm,
                      float* __restrict__ kappaWs,
                      int* __restrict__ idxWs) {
  const int t    = threadIdx.x;
  const int lane = t & 63;
  const int w    = t >> 6;
  const int i    = blockIdx.x * 4 + w;     // query point
  const int b    = blockIdx.y;
  const int ds   = blockIdx.z;

  const float* __restrict__ P  = (ds == 0 ? ori : adv) + (size_t)b * 3 * NPTS;
  const float* __restrict__ Xp = P;
  const float* __restrict__ Yp = P + NPTS;
  const float* __restrict__ Zp = P + 2 * NPTS;

  const float xi = Xp[i], yi = Yp[i], zi = Zp[i];
  const int ichunk = i >> 6;

  // ---- chunk 0: seed list with bitonic sort of first 64 candidates ----
  float ld;  int lj;
  {
    const int j = lane;
    const float dx = Xp[j] - xi;
    const float dy = Yp[j] - yi;
    const float dz = Zp[j] - zi;
    float d2 = fmaf(dx, dx, fmaf(dy, dy, dz * dz));
    if (ichunk == 0 && j == i) d2 = BIG;       // exclude self
    int s = j;
    bitonic_sort64(d2, s, lane);
    ld = d2; lj = s;                            // lanes 0..15 = top-16 sorted
  }
  float tau = __shfl(ld, 15);

  // ---- chunks 1..63: gated scan with software-pipelined loads ----
  float px = Xp[64 + lane], py = Yp[64 + lane], pz = Zp[64 + lane];
  for (int c = 1; c < 64; ++c) {
    const float cx = px, cy = py, cz = pz;
    if (c + 1 < 64) {
      const int jn = (c + 1) * 64 + lane;
      px = Xp[jn]; py = Yp[jn]; pz = Zp[jn];
    }
    const int j = c * 64 + lane;
    const float dx = cx - xi;
    const float dy = cy - yi;
    const float dz = cz - zi;
    float d2 = fmaf(dx, dx, fmaf(dy, dy, dz * dz));
    if (c == ichunk) { if (j == i) d2 = BIG; } // self only in its own chunk

    unsigned long long m = __ballot(d2 < tau);
    while (m) {
      const int wl = __ffsll(m) - 1;
      const float dn = __shfl(d2, wl);
      const int   jn = c * 64 + wl;
      // sorted insert: first list lane with ld > dn is the insert position
      const bool gt = (lane < KNB) && (ld > dn);
      const unsigned long long gm = __ballot(gt);
      const int pos = __ffsll(gm) - 1;          // exists: dn < tau = ld[15]
      const float sld = __shfl_up(ld, 1);
      const int   slj = __shfl_up(lj, 1);
      if (lane >= pos && lane < KNB) {
        ld = (lane == pos) ? dn : sld;
        lj = (lane == pos) ? jn : slj;
      }
      tau = __shfl(ld, 15);
      m &= ~(1ull << wl);
      m &= __ballot(d2 < tau);                  // drop no-longer-qualifying
    }
  }

  // ---- kappa + index output (lanes 0..15 hold the 16 nearest) ----
  const float* __restrict__ nb_ = nrm + (size_t)b * 3 * NPTS;
  const float nx = nb_[i], ny = nb_[NPTS + i], nz = nb_[2 * NPTS + i];
  float c = 0.f;
  if (lane < KNB) {
    const int nbj = lj;
    const float vx = Xp[nbj] - xi, vy = Yp[nbj] - yi, vz = Zp[nbj] - zi;
    float L = fmaxf(sqrtf(fmaf(vx, vx, fmaf(vy, vy, vz * vz))), 1e-12f);
    c = fabsf(fmaf(vx, nx, fmaf(vy, ny, vz * nz)) / L);
  }
  c += __shfl_xor(c, 1);
  c += __shfl_xor(c, 2);
  c += __shfl_xor(c, 4);
  c += __shfl_xor(c, 8);
  const size_t row = (size_t)(ds * BATCH + b) * NPTS + i;
  if (lane == 0) kappaWs[row] = c * (1.0f / 16.0f);
  if (lane < KNB) idxWs[row * KNB + lane] = lj;
}

// ---------------------------------------------------------------------------
// Kernel 2: per (b,i): gather 16 neighbor kappas for both datasets, std with
// ddof=1, d = std_ori - std_adv + 1e-6, block-reduce d^2 into partials.
// ---------------------------------------------------------------------------
__global__ __launch_bounds__(256)
void std_dist_kernel(const float* __restrict__ kappaWs,
                     const int* __restrict__ idxWs,
                     float* __restrict__ partial) {
  const int i = blockIdx.x * 256 + threadIdx.x;
  const int b = blockIdx.y;

  float s[2];
#pragma unroll
  for (int ds = 0; ds < 2; ++ds) {
    const size_t kb = (size_t)(ds * BATCH + b) * NPTS;
    const int* __restrict__ ip = idxWs + (kb + i) * KNB;
    float kv[16];
    float sum = 0.f;
#pragma unroll
    for (int u = 0; u < 16; ++u) {
      kv[u] = kappaWs[kb + ip[u]];
      sum += kv[u];
    }
    const float mean = sum * (1.0f / 16.0f);
    float ss = 0.f;
#pragma unroll
    for (int u = 0; u < 16; ++u) {
      const float dv = kv[u] - mean;
      ss = fmaf(dv, dv, ss);
    }
    s[ds] = sqrtf(ss * (1.0f / 15.0f));   // unbiased (ddof=1)
  }

  float dq = s[0] - s[1] + 1e-6f;          // PairwiseDistance eps inside norm
  dq = dq * dq;

  dq += __shfl_xor(dq, 32);
  dq += __shfl_xor(dq, 16);
  dq += __shfl_xor(dq, 8);
  dq += __shfl_xor(dq, 4);
  dq += __shfl_xor(dq, 2);
  dq += __shfl_xor(dq, 1);
  __shared__ float red[4];
  if ((threadIdx.x & 63) == 0) red[threadIdx.x >> 6] = dq;
  __syncthreads();
  if (threadIdx.x == 0)
    partial[b * 16 + blockIdx.x] = red[0] + red[1] + red[2] + red[3];
}

// ---------------------------------------------------------------------------
// Kernel 3: 64 partials (4 batches x 16 blocks) -> mean_b sqrt(sum_b)
// ---------------------------------------------------------------------------
__global__ void finalize_kernel(const float* __restrict__ partial,
                                float* __restrict__ out) {
  const int l = threadIdx.x;   // 64 threads
  float v = partial[l];
  v += __shfl_xor(v, 1);
  v += __shfl_xor(v, 2);
  v += __shfl_xor(v, 4);
  v += __shfl_xor(v, 8);
  float s = sqrtf(v);
  s += __shfl_xor(s, 16);
  s += __shfl_xor(s, 32);
  if (l == 0) out[0] = s * 0.25f;
}

extern "C" void kernel_launch(void* const* d_in, const int* in_sizes, int n_in,
                              void* d_out, int out_size, void* d_ws, size_t ws_size,
                              hipStream_t stream) {
  const float* ori = (const float*)d_in[0];
  const float* adv = (const float*)d_in[1];
  const float* nrm = (const float*)d_in[2];
  float* out = (float*)d_out;

  float* kappaWs = (float*)d_ws;                                  // 2*4*4096 f32
  int*   idxWs   = (int*)((char*)d_ws + (size_t)2 * BATCH * NPTS * 4);
  float* partial = (float*)((char*)d_ws + (size_t)2 * BATCH * NPTS * 4
                                        + (size_t)2 * BATCH * NPTS * KNB * 4);

  dim3 g1(NPTS / 4, BATCH, 2);
  knn_kappa_kernel<<<g1, 256, 0, stream>>>(ori, adv, nrm, kappaWs, idxWs);

  dim3 g2(NPTS / 256, BATCH);
  std_dist_kernel<<<g2, 256, 0, stream>>>(kappaWs, idxWs, partial);

  finalize_kernel<<<dim3(1), 64, 0, stream>>>(partial, out);
}

// Round 5
// 149.571 us; speedup vs baseline: 1.2665x; 1.2665x over previous
//
#include <hip/hip_runtime.h>
#include <math.h>

#define NPTS 4096
#define BATCH 4
#define KNB 16
#define BIG 3.0e38f
#define CAP 1024   // survivor capacity (expected M ~40-70 for random data)

// ---------------------------------------------------------------------------
// Bitonic sort of 64 (d,slot) pairs, one per lane, ascending in d.
// ---------------------------------------------------------------------------
__device__ __forceinline__ void bsort_stage(float& d, int& s, int lane, int k, int j) {
  const float od = __shfl_xor(d, j);
  const int   os = __shfl_xor(s, j);
  const bool keepMin = ((lane & k) == 0) == ((lane & j) == 0);
  const bool takeO = keepMin ? (od < d) : (od > d);
  d = takeO ? od : d;
  s = takeO ? os : s;
}

__device__ __forceinline__ void bitonic_sort64(float& d, int& s, int lane) {
#pragma unroll
  for (int k = 2; k <= 64; k <<= 1) {
#pragma unroll
    for (int j = k >> 1; j >= 1; j >>= 1)
      bsort_stage(d, s, lane, k, j);
  }
}

__device__ __forceinline__ void bitonic_merge64(float& d, int& s, int lane) {
#pragma unroll
  for (int j = 32; j >= 1; j >>= 1)
    bsort_stage(d, s, lane, 64, j);   // k=64: ascending everywhere
}

// Values-only variant for the thread-min sort (cheaper: no index shuffles).
__device__ __forceinline__ void bitonic_sort64_v(float& d, int lane) {
#pragma unroll
  for (int k = 2; k <= 64; k <<= 1) {
#pragma unroll
    for (int j = k >> 1; j >= 1; j >>= 1) {
      const float od = __shfl_xor(d, j);
      const bool keepMin = ((lane & k) == 0) == ((lane & j) == 0);
      d = keepMin ? fminf(d, od) : fmaxf(d, od);
    }
  }
}

// ---------------------------------------------------------------------------
// Kernel 1: one block (256 thr) per (point i, batch b, dataset ds).
// Exact 16-NN: per-thread-min -> per-wave 16th-order-stat -> tau = min over
// waves (provably >= true d16) -> collect survivors -> one bitonic sort.
// ---------------------------------------------------------------------------
__global__ __launch_bounds__(256)
void knn_kappa_kernel(const float* __restrict__ ori,
                      const float* __restrict__ adv,
                      const float* __restrict__ nrm,
                      float* __restrict__ kappaWs,
                      int* __restrict__ idxWs) {
  const int i    = blockIdx.x;
  const int b    = blockIdx.y;
  const int ds   = blockIdx.z;
  const int t    = threadIdx.x;
  const int lane = t & 63;
  const int w    = t >> 6;

  const float* __restrict__ P  = (ds == 0 ? ori : adv) + (size_t)b * 3 * NPTS;
  const float* __restrict__ Xp = P;
  const float* __restrict__ Yp = P + NPTS;
  const float* __restrict__ Zp = P + 2 * NPTS;

  __shared__ float candD[CAP];
  __shared__ int   candI[CAP];
  __shared__ float wTau[4];
  __shared__ unsigned int cnt;

  if (t == 0) cnt = 0;

  const float xi = Xp[i], yi = Yp[i], zi = Zp[i];

  // Distance pass: 16 candidates per thread (registers), track thread min.
  float d[16];
  float tmin = BIG;
#pragma unroll
  for (int u = 0; u < 16; ++u) {
    const int j = u * 256 + t;
    const float dx = Xp[j] - xi;
    const float dy = Yp[j] - yi;
    const float dz = Zp[j] - zi;
    float d2 = fmaf(dx, dx, fmaf(dy, dy, dz * dz));
    if (j == i) d2 = BIG;          // exclude self
    d[u] = d2;
    tmin = fminf(tmin, d2);
  }

  // Per-wave: 16th smallest of the 64 thread-mins = tau_w.
  float sm = tmin;
  bitonic_sort64_v(sm, lane);
  if (lane == (KNB - 1)) wTau[w] = sm;
  __syncthreads();
  const float tau = fminf(fminf(wTau[0], wTau[1]), fminf(wTau[2], wTau[3]));

  // Collect survivors (d2 <= tau). Guaranteed to include the true top-16.
#pragma unroll
  for (int u = 0; u < 16; ++u) {
    if (d[u] <= tau) {
      const unsigned pos = atomicAdd(&cnt, 1u);
      if (pos < CAP) { candD[pos] = d[u]; candI[pos] = u * 256 + t; }
    }
  }
  __syncthreads();

  // Wave 0: exact top-16 of the M survivors via bitonic sort (+merge if >64).
  if (w == 0) {
    const int M = (int)(cnt < CAP ? cnt : CAP);
    float sd = (lane < M) ? candD[lane] : BIG;
    int   si = (lane < M) ? lane : -1;
    bitonic_sort64(sd, si, lane);
    for (int c0 = 64; c0 < M; c0 += 64) {       // uncommon: M > 64
      const int slot = c0 + lane;
      float vd = (slot < M) ? candD[slot] : BIG;
      int   vi = (slot < M) ? slot : -1;
      bitonic_sort64(vd, vi, lane);
      const float rd = __shfl_xor(vd, 63);      // reverse -> descending
      const int   ri = __shfl_xor(vi, 63);
      if (rd < sd) { sd = rd; si = ri; }        // min-half of bitonic merge
      bitonic_merge64(sd, si, lane);            // re-sort ascending
    }

    // lanes 0..15 hold the 16 nearest (ascending). Kappa + idx out.
    if (lane < KNB) {
      const int nbj = candI[si];
      const float px = Xp[nbj], py = Yp[nbj], pz = Zp[nbj];
      const float vx = px - xi, vy = py - yi, vz = pz - zi;
      float L = sqrtf(fmaf(vx, vx, fmaf(vy, vy, vz * vz)));
      L = fmaxf(L, 1e-12f);
      const float* __restrict__ nb_ = nrm + (size_t)b * 3 * NPTS;
      const float nx = nb_[i], ny = nb_[NPTS + i], nz = nb_[2 * NPTS + i];
      float c = fabsf(fmaf(vx, nx, fmaf(vy, ny, vz * nz)) / L);
      c += __shfl_xor(c, 1);
      c += __shfl_xor(c, 2);
      c += __shfl_xor(c, 4);
      c += __shfl_xor(c, 8);
      const size_t row = (size_t)(ds * BATCH + b) * NPTS + i;
      if (lane == 0) kappaWs[row] = c * (1.0f / 16.0f);
      idxWs[row * KNB + lane] = nbj;
    }
  }
}

// ---------------------------------------------------------------------------
// Kernel 2: per (b,i): gather 16 neighbor kappas for both datasets, std with
// ddof=1, d = std_ori - std_adv + 1e-6, block-reduce d^2 into partials.
// ---------------------------------------------------------------------------
__global__ __launch_bounds__(256)
void std_dist_kernel(const float* __restrict__ kappaWs,
                     const int* __restrict__ idxWs,
                     float* __restrict__ partial) {
  const int i = blockIdx.x * 256 + threadIdx.x;
  const int b = blockIdx.y;

  float s[2];
#pragma unroll
  for (int ds = 0; ds < 2; ++ds) {
    const size_t kb = (size_t)(ds * BATCH + b) * NPTS;
    const int* __restrict__ ip = idxWs + (kb + i) * KNB;
    float kv[16];
    float sum = 0.f;
#pragma unroll
    for (int u = 0; u < 16; ++u) {
      kv[u] = kappaWs[kb + ip[u]];
      sum += kv[u];
    }
    const float mean = sum * (1.0f / 16.0f);
    float ss = 0.f;
#pragma unroll
    for (int u = 0; u < 16; ++u) {
      const float dv = kv[u] - mean;
      ss = fmaf(dv, dv, ss);
    }
    s[ds] = sqrtf(ss * (1.0f / 15.0f));   // unbiased (ddof=1)
  }

  float dq = s[0] - s[1] + 1e-6f;          // PairwiseDistance eps inside norm
  dq = dq * dq;

  dq += __shfl_xor(dq, 32);
  dq += __shfl_xor(dq, 16);
  dq += __shfl_xor(dq, 8);
  dq += __shfl_xor(dq, 4);
  dq += __shfl_xor(dq, 2);
  dq += __shfl_xor(dq, 1);
  __shared__ float red[4];
  if ((threadIdx.x & 63) == 0) red[threadIdx.x >> 6] = dq;
  __syncthreads();
  if (threadIdx.x == 0)
    partial[b * 16 + blockIdx.x] = red[0] + red[1] + red[2] + red[3];
}

// ---------------------------------------------------------------------------
// Kernel 3: 64 partials (4 batches x 16 blocks) -> mean_b sqrt(sum_b)
// ---------------------------------------------------------------------------
__global__ void finalize_kernel(const float* __restrict__ partial,
                                float* __restrict__ out) {
  const int l = threadIdx.x;   // 64 threads
  float v = partial[l];
  v += __shfl_xor(v, 1);
  v += __shfl_xor(v, 2);
  v += __shfl_xor(v, 4);
  v += __shfl_xor(v, 8);
  float s = sqrtf(v);
  s += __shfl_xor(s, 16);
  s += __shfl_xor(s, 32);
  if (l == 0) out[0] = s * 0.25f;
}

extern "C" void kernel_launch(void* const* d_in, const int* in_sizes, int n_in,
                              void* d_out, int out_size, void* d_ws, size_t ws_size,
                              hipStream_t stream) {
  const float* ori = (const float*)d_in[0];
  const float* adv = (const float*)d_in[1];
  const float* nrm = (const float*)d_in[2];
  float* out = (float*)d_out;

  float* kappaWs = (float*)d_ws;                                  // 2*4*4096 f32
  int*   idxWs   = (int*)((char*)d_ws + (size_t)2 * BATCH * NPTS * 4);
  float* partial = (float*)((char*)d_ws + (size_t)2 * BATCH * NPTS * 4
                                        + (size_t)2 * BATCH * NPTS * KNB * 4);

  dim3 g1(NPTS, BATCH, 2);
  knn_kappa_kernel<<<g1, 256, 0, stream>>>(ori, adv, nrm, kappaWs, idxWs);

  dim3 g2(NPTS / 256, BATCH);
  std_dist_kernel<<<g2, 256, 0, stream>>>(kappaWs, idxWs, partial);

  finalize_kernel<<<dim3(1), 64, 0, stream>>>(partial, out);
}